// Round 4
// baseline (842.245 us; speedup 1.0000x reference)
//
#include <hip/hip_runtime.h>
#include <math.h>

#define NTOK 4096
#define DDIM 1024
#define IDIM 4096
#define NEXP 8
#define MAXPAD 9216   // 8192 assignments + 8*128 worst-case 128-padded layout

typedef _Float16 f16x8 __attribute__((ext_vector_type(8)));
typedef _Float16 f16x4 __attribute__((ext_vector_type(4)));
typedef float    f32x4 __attribute__((ext_vector_type(4)));

// ---------------- async global->LDS, 16B per lane, lane-ordered LDS dest ----
__device__ __forceinline__ void glds16(const _Float16* g, _Float16* l) {
    __builtin_amdgcn_global_load_lds(
        (const __attribute__((address_space(1))) _Float16*)g,
        (__attribute__((address_space(3))) _Float16*)l, 16, 0, 0);
}

// tanh-approx GELU: |err| vs exact erf-GELU <= ~3e-3, far under our margin.
__device__ __forceinline__ float fast_gelu(float v) {
    float u = v * (0.7978845608f + 0.0356774081f * v * v);
    float ex = __builtin_amdgcn_exp2f(u * 2.8853900817779268f);  // exp(2u)
    float th = 1.0f - 2.0f * __builtin_amdgcn_rcpf(ex + 1.0f);   // tanh(u)
    return 0.5f * v * (1.0f + th);
}

// ---------------- fp32 -> fp16 weight conversion ----------------------------
__global__ void cvt_kernel(const float* __restrict__ src, _Float16* __restrict__ dst, int n4) {
    int i = blockIdx.x * blockDim.x + threadIdx.x;
    if (i >= n4) return;
    float4 v = ((const float4*)src)[i];
    f16x4 o = { (_Float16)v.x, (_Float16)v.y, (_Float16)v.z, (_Float16)v.w };
    ((f16x4*)dst)[i] = o;
}

// ---------------- gating: logits, top-2, softmax, atomic append -------------
__global__ void gate_kernel(const float* __restrict__ x, const float* __restrict__ gw,
                            const float* __restrict__ gb,
                            int* __restrict__ cnt, int* __restrict__ tok,
                            float* __restrict__ wgt) {
    int wave = threadIdx.x >> 6;
    int lane = threadIdx.x & 63;
    int token = blockIdx.x * 4 + wave;
    const float* xr = x + (size_t)token * DDIM;
    float xv[16];
#pragma unroll
    for (int j = 0; j < 16; ++j) xv[j] = xr[lane + 64 * j];
    float lg[NEXP];
#pragma unroll
    for (int e = 0; e < NEXP; ++e) {
        const float* g = gw + e * DDIM;
        float s = 0.f;
#pragma unroll
        for (int j = 0; j < 16; ++j) s += xv[j] * g[lane + 64 * j];
#pragma unroll
        for (int o = 32; o > 0; o >>= 1) s += __shfl_xor(s, o, 64);
        lg[e] = s + gb[e];
    }
    if (lane == 0) {
        int i0 = 0; float v0 = lg[0];
        for (int e = 1; e < NEXP; ++e) if (lg[e] > v0) { v0 = lg[e]; i0 = e; }
        int i1 = -1; float v1 = -3.0e38f;
        for (int e = 0; e < NEXP; ++e) { if (e == i0) continue; if (lg[e] > v1) { v1 = lg[e]; i1 = e; } }
        float e1 = expf(v1 - v0);
        float den = 1.f + e1;
        float w0 = 1.f / den;
        float w1 = e1 / den;
        int p0 = atomicAdd(&cnt[i0], 1);
        tok[i0 * NTOK + p0] = token; wgt[i0 * NTOK + p0] = w0;
        int p1 = atomicAdd(&cnt[i1], 1);
        tok[i1 * NTOK + p1] = token; wgt[i1 * NTOK + p1] = w1;
    }
}

// ------ prefix scan of 128-padded expert counts + build tile work queues ----
// q1: GEMM1 entries (e, mt, nt)          -- <= ~640 entries
// q2: GEMM2 entries (e, mt, nt, kc x4)   -- <= ~640 entries
// entry encode: e | mt<<4 | nt<<12 | kc<<20
__global__ void scan_kernel(const int* __restrict__ cnt, int* __restrict__ off,
                            int* __restrict__ q1, int* __restrict__ q2) {
    if (threadIdx.x == 0) {
        int acc = 0;
        for (int e = 0; e < NEXP; ++e) { off[e] = acc; acc += ((cnt[e] + 127) >> 7) << 7; }
        off[NEXP] = acc;
        int n1 = 0, n2 = 0;
        for (int e = 0; e < NEXP; ++e) {
            int mtiles = (cnt[e] + 255) >> 8;
            for (int mt = 0; mt < mtiles; ++mt) {
                for (int nt = 0; nt < IDIM / 256; ++nt)
                    q1[n1++] = e | (mt << 4) | (nt << 12);
                for (int kc = 0; kc < 4; ++kc)
                    for (int nt = 0; nt < DDIM / 256; ++nt)
                        q2[n2++] = e | (mt << 4) | (nt << 12) | (kc << 20);
            }
        }
        off[10] = n1; off[11] = n2;
    }
}

// ---------------- gather tokens into compacted fp16 activation rows ---------
__global__ void gather_kernel(const float* __restrict__ x, const int* __restrict__ cnt,
                              const int* __restrict__ off, const int* __restrict__ tok,
                              _Float16* __restrict__ xg) {
    int row = blockIdx.x;
    if (row >= off[NEXP]) return;
    int e = 0;
    while (e < NEXP - 1 && row >= off[e + 1]) ++e;
    int r = row - off[e];
    int t = threadIdx.x;
    _Float16* dst = xg + (size_t)row * DDIM;
    if (r < cnt[e]) {
        int token = tok[e * NTOK + r];
        float4 v = ((const float4*)(x + (size_t)token * DDIM))[t];
        f16x4 o = { (_Float16)v.x, (_Float16)v.y, (_Float16)v.z, (_Float16)v.w };
        ((f16x4*)dst)[t] = o;
    } else {
        f16x4 z = {};
        ((f16x4*)dst)[t] = z;   // zero padding rows so edge tiles are benign
    }
}

// ============================================================================
// Persistent 256x256 grouped GEMM, BK=64, 8 waves (2M x 4N), dbuf 128 KiB LDS.
// Grid = 256 blocks exactly -> 1 resident block per CU (round-2 counters:
// 1024-block grid kept only ~44% of CUs busy; kernel is staging-BW-bound so
// CU coverage is the binding term). Work assignment is DETERMINISTIC strided:
// block b runs device-built queue entries b, b+256, ... (no atomics, no LDS
// broadcast -- makespan identical to a dynamic queue for uniform entries).
// Inner tile pipeline identical to round 2 (correctness-proven):
//   [issue ALL 8 next-tile glds] -> s_waitcnt vmcnt(8) -> s_barrier ->
//   24 ds_read_b128 + 64 MFMA (4 reuse clusters, setprio(1) wrapped) ->
//   lgkmcnt(0) -> s_barrier.   XOR swizzle (row&7) both-sides, conflicts=0.
// EPI==1: h = gelu(A@W1^T + b1) -> fp16.  EPI==2: out += w*(A@W2^T + b2).
// ============================================================================
#define SBAR() do { __builtin_amdgcn_s_barrier(); asm volatile("" ::: "memory"); } while (0)
#define STA(b, s, ko) glds16(ap[s] + (ko), &As[b][((s) * 64 + wv * 8) * 64])
#define STB(b, s, ko) glds16(bp[s] + (ko), &Bs[b][((s) * 64 + wv * 8) * 64])
#define ARD(buf, row, kb) (*(const f16x8*)&As[buf][(row) * 64 + ((((kb) + fq) ^ ((row) & 7)) << 3)])
#define BRD(buf, row, kb) (*(const f16x8*)&Bs[buf][(row) * 64 + ((((kb) + fq) ^ ((row) & 7)) << 3)])

template <int KDIM, int NDIM, int EPI, int SPLIT>
__global__ __launch_bounds__(512, 2) void gemm256_kernel(
    const _Float16* __restrict__ A,     // [MAXPAD][KDIM] compacted rows
    const _Float16* __restrict__ Bw,    // [E][NDIM][KDIM] (K-major / B^T form)
    const float* __restrict__ bias,     // [E][NDIM]
    const int* __restrict__ cnt, const int* __restrict__ off,
    const int* __restrict__ tok, const float* __restrict__ wgt,
    _Float16* __restrict__ Hout, float* __restrict__ Out,
    const int* __restrict__ qarr, const int* __restrict__ qn) {
    constexpr int KB = KDIM / SPLIT;    // K elements per split group
    constexpr int NK = KB / 64;         // K-tiles of 64

    __shared__ __align__(16) _Float16 As[2][256 * 64];   // 64 KiB
    __shared__ __align__(16) _Float16 Bs[2][256 * 64];   // 64 KiB

    const int tid = threadIdx.x;
    const int wv = tid >> 6, lane = tid & 63;
    const int wm = (wv >> 2) * 128;     // wave row offset (2 waves in M)
    const int wn = (wv & 3) * 64;       // wave col offset (4 waves in N)
    const int fr = lane & 15, fq = lane >> 4;
    const int srow = lane >> 3;                 // 0..7 row within wave slice
    const int scol = ((lane & 7) ^ srow) << 3;  // swizzled source col element
    const int nwork = *qn;

    for (int wi = blockIdx.x; wi < nwork; wi += gridDim.x) {
        __syncthreads();                       // prev entry fully done (LDS reuse safe)
        const int w = qarr[wi];
        const int e  = w & 15;
        const int mt = (w >> 4) & 63;
        const int nt = (w >> 12) & 63;
        const int kc = (w >> 20) & 7;
        const int ce = cnt[e];
        const int rowbase = off[e] + mt * 256;
        const int colbase = nt * 256;

        // staging: per glds a wave covers 8 rows x 64 elems (1 KiB, linear LDS).
        // source col pre-swizzled so LDS[r][c16] = G[r][c16 ^ (r&7)].
        const _Float16* ap[4];
        const _Float16* bp[4];
#pragma unroll
        for (int s = 0; s < 4; ++s) {
            int ra = rowbase + s * 64 + wv * 8 + srow;
            if (ra > MAXPAD - 1) ra = MAXPAD - 1;   // clamp: garbage discarded in epilogue
            ap[s] = A + (size_t)ra * KDIM + kc * KB + scol;
            bp[s] = Bw + ((size_t)e * NDIM + colbase + s * 64 + wv * 8 + srow) * KDIM + kc * KB + scol;
        }

        f32x4 acc[8][4] = {};

        // prologue: stage K-tile 0 into buffer 0 (8 glds per wave)
        STA(0, 0, 0); STA(0, 1, 0); STA(0, 2, 0); STA(0, 3, 0);
        STB(0, 0, 0); STB(0, 1, 0); STB(0, 2, 0); STB(0, 3, 0);

        for (int kt = 0; kt < NK; ++kt) {
            const int cur = kt & 1, nxt = cur ^ 1;
            const int ko = (kt + 1) * 64;
            f16x8 a[4], b[4];
            // ---- issue ENTIRE next K-tile now: full-iteration prefetch ----
            if (kt + 1 < NK) {
                STA(nxt, 0, ko); STA(nxt, 1, ko); STA(nxt, 2, ko); STA(nxt, 3, ko);
                STB(nxt, 0, ko); STB(nxt, 1, ko); STB(nxt, 2, ko); STB(nxt, 3, ko);
                asm volatile("s_waitcnt vmcnt(8)" ::: "memory");  // cur's 8 done, next 8 in flight
            } else {
                asm volatile("s_waitcnt vmcnt(0)" ::: "memory");
            }
            SBAR();   // all waves' cur-tile loads arrived
            // ---- cluster 1: rows wm.., k-slice 0 --------------------------
#pragma unroll
            for (int i = 0; i < 4; ++i) a[i] = ARD(cur, wm + i * 16 + fr, 0);
#pragma unroll
            for (int j = 0; j < 4; ++j) b[j] = BRD(cur, wn + j * 16 + fr, 0);
            __builtin_amdgcn_s_setprio(1);
#pragma unroll
            for (int i = 0; i < 4; ++i)
#pragma unroll
                for (int j = 0; j < 4; ++j)
                    acc[i][j] = __builtin_amdgcn_mfma_f32_16x16x32_f16(a[i], b[j], acc[i][j], 0, 0, 0);
            __builtin_amdgcn_s_setprio(0);
            // ---- cluster 2: rows wm+64.., k-slice 0 (b reused) ------------
#pragma unroll
            for (int i = 0; i < 4; ++i) a[i] = ARD(cur, wm + 64 + i * 16 + fr, 0);
            __builtin_amdgcn_s_setprio(1);
#pragma unroll
            for (int i = 0; i < 4; ++i)
#pragma unroll
                for (int j = 0; j < 4; ++j)
                    acc[i + 4][j] = __builtin_amdgcn_mfma_f32_16x16x32_f16(a[i], b[j], acc[i + 4][j], 0, 0, 0);
            __builtin_amdgcn_s_setprio(0);
            // ---- cluster 3: rows wm+64.., k-slice 1 -----------------------
#pragma unroll
            for (int i = 0; i < 4; ++i) a[i] = ARD(cur, wm + 64 + i * 16 + fr, 4);
#pragma unroll
            for (int j = 0; j < 4; ++j) b[j] = BRD(cur, wn + j * 16 + fr, 4);
            __builtin_amdgcn_s_setprio(1);
#pragma unroll
            for (int i = 0; i < 4; ++i)
#pragma unroll
                for (int j = 0; j < 4; ++j)
                    acc[i + 4][j] = __builtin_amdgcn_mfma_f32_16x16x32_f16(a[i], b[j], acc[i + 4][j], 0, 0, 0);
            __builtin_amdgcn_s_setprio(0);
            // ---- cluster 4: rows wm.., k-slice 1 (b reused) ---------------
#pragma unroll
            for (int i = 0; i < 4; ++i) a[i] = ARD(cur, wm + i * 16 + fr, 4);
            __builtin_amdgcn_s_setprio(1);
#pragma unroll
            for (int i = 0; i < 4; ++i)
#pragma unroll
                for (int j = 0; j < 4; ++j)
                    acc[i][j] = __builtin_amdgcn_mfma_f32_16x16x32_f16(a[i], b[j], acc[i][j], 0, 0, 0);
            __builtin_amdgcn_s_setprio(0);
            // all LDS reads of `cur` must retire before next iter restages it
            asm volatile("s_waitcnt lgkmcnt(0)" ::: "memory");
            SBAR();
        }

        // -------- epilogue: acc[q] -> rows wm + (q>>2)*64 + (q&3)*16 --------
        const int rq = fq << 2;   // C/D: row = (lane>>4)*4 + reg, col = lane&15
        if constexpr (EPI == 1) {
            const int elim = off[e + 1];   // stay inside this expert's 128-padded region
#pragma unroll
            for (int q = 0; q < 8; ++q) {
                const int rbase = wm + ((q >> 2) * 64) + ((q & 3) * 16) + rq;
#pragma unroll
                for (int r = 0; r < 4; ++r) {
                    const int grow = rowbase + rbase + r;
                    if (grow < elim) {
#pragma unroll
                        for (int j = 0; j < 4; ++j) {
                            const int col = colbase + wn + j * 16 + fr;
                            float v = fast_gelu(acc[q][j][r] + bias[e * NDIM + col]);
                            Hout[(size_t)grow * NDIM + col] = (_Float16)v;
                        }
                    }
                }
            }
        } else {
#pragma unroll
            for (int q = 0; q < 8; ++q) {
                const int rbase = wm + ((q >> 2) * 64) + ((q & 3) * 16) + rq;
#pragma unroll
                for (int r = 0; r < 4; ++r) {
                    const int slot = mt * 256 + rbase + r;
                    if (slot < ce) {
                        const int token = tok[e * NTOK + slot];
                        const float ww = wgt[e * NTOK + slot];
#pragma unroll
                        for (int j = 0; j < 4; ++j) {
                            const int col = colbase + wn + j * 16 + fr;
                            float v = acc[q][j][r];
                            if (kc == 0) v += bias[e * NDIM + col];  // bias once per split group
                            unsafeAtomicAdd(&Out[(size_t)token * NDIM + col], ww * v);
                        }
                    }
                }
            }
        }
    }
}

extern "C" void kernel_launch(void* const* d_in, const int* in_sizes, int n_in,
                              void* d_out, int out_size, void* d_ws, size_t ws_size,
                              hipStream_t stream) {
    const float* x      = (const float*)d_in[0];
    const float* gate_w = (const float*)d_in[1];
    const float* gate_b = (const float*)d_in[2];
    const float* w1     = (const float*)d_in[3];
    const float* b1     = (const float*)d_in[4];
    const float* w2     = (const float*)d_in[5];
    const float* b2     = (const float*)d_in[6];
    float* out = (float*)d_out;

    // workspace layout (~218.5 MB)
    char* p = (char*)d_ws;
    _Float16* w1h  = (_Float16*)p; p += (size_t)NEXP * IDIM * DDIM * 2;  // 64 MB
    _Float16* w2h  = (_Float16*)p; p += (size_t)NEXP * DDIM * IDIM * 2;  // 64 MB
    _Float16* xg   = (_Float16*)p; p += (size_t)MAXPAD * DDIM * 2;       // 18 MB
    _Float16* hbuf = (_Float16*)p; p += (size_t)MAXPAD * IDIM * 2;       // 72 MB
    int*      tok  = (int*)p;      p += (size_t)NEXP * NTOK * 4;
    float*    wgt  = (float*)p;    p += (size_t)NEXP * NTOK * 4;
    int*      cnt  = (int*)p;      p += 128;   // [0..7] expert counts
    int*      off  = (int*)p;      p += 128;   // [0..8] offsets, [10] n1, [11] n2
    int*      q1   = (int*)p;      p += 4096;  // GEMM1 tile queue (1024 ints)
    int*      q2   = (int*)p;      p += 4096;  // GEMM2 tile queue (1024 ints)

    hipMemsetAsync(cnt, 0, 128, stream);
    hipMemsetAsync(out, 0, (size_t)NTOK * DDIM * 4, stream);

    cvt_kernel<<<32768, 256, 0, stream>>>(w1, w1h, NEXP * IDIM * DDIM / 4);
    cvt_kernel<<<32768, 256, 0, stream>>>(w2, w2h, NEXP * DDIM * IDIM / 4);
    gate_kernel<<<NTOK / 4, 256, 0, stream>>>(x, gate_w, gate_b, cnt, tok, wgt);
    scan_kernel<<<1, 64, 0, stream>>>(cnt, off, q1, q2);
    gather_kernel<<<MAXPAD, 256, 0, stream>>>(x, cnt, off, tok, xg);

    // GEMM1: [rows x 1024] @ w1[e]^T -> gelu -> h [rows x 4096]
    gemm256_kernel<DDIM, IDIM, 1, 1><<<dim3(256), 512, 0, stream>>>(
        xg, w1h, b1, cnt, off, tok, wgt, hbuf, (float*)nullptr, q1, off + 10);
    // GEMM2: [rows x 4096] @ w2[e]^T -> scaled scatter-add into out, split-K x4
    gemm256_kernel<IDIM, DDIM, 2, 4><<<dim3(256), 512, 0, stream>>>(
        hbuf, w2h, b2, cnt, off, tok, wgt, (_Float16*)nullptr, out, q2, off + 11);
}

// Round 5
// 781.045 us; speedup vs baseline: 1.0784x; 1.0784x over previous
//
#include <hip/hip_runtime.h>
#include <math.h>

#define NTOK 4096
#define DDIM 1024
#define IDIM 4096
#define NEXP 8
#define MAXPAD 9216   // 8192 assignments + 8*128 worst-case 128-padded layout

typedef _Float16 f16x8 __attribute__((ext_vector_type(8)));
typedef _Float16 f16x4 __attribute__((ext_vector_type(4)));
typedef float    f32x4 __attribute__((ext_vector_type(4)));

// ---------------- async global->LDS, 16B per lane, lane-ordered LDS dest ----
__device__ __forceinline__ void glds16(const _Float16* g, _Float16* l) {
    __builtin_amdgcn_global_load_lds(
        (const __attribute__((address_space(1))) _Float16*)g,
        (__attribute__((address_space(3))) _Float16*)l, 16, 0, 0);
}

// tanh-approx GELU: |err| vs exact erf-GELU <= ~3e-3, far under our margin.
__device__ __forceinline__ float fast_gelu(float v) {
    float u = v * (0.7978845608f + 0.0356774081f * v * v);
    float ex = __builtin_amdgcn_exp2f(u * 2.8853900817779268f);  // exp(2u)
    float th = 1.0f - 2.0f * __builtin_amdgcn_rcpf(ex + 1.0f);   // tanh(u)
    return 0.5f * v * (1.0f + th);
}

// ---------------- fp32 -> fp16 weight conversion ----------------------------
__global__ void cvt_kernel(const float* __restrict__ src, _Float16* __restrict__ dst, int n4) {
    int i = blockIdx.x * blockDim.x + threadIdx.x;
    if (i >= n4) return;
    float4 v = ((const float4*)src)[i];
    f16x4 o = { (_Float16)v.x, (_Float16)v.y, (_Float16)v.z, (_Float16)v.w };
    ((f16x4*)dst)[i] = o;
}

// ---------------- gating: logits, top-2, softmax, atomic append -------------
__global__ void gate_kernel(const float* __restrict__ x, const float* __restrict__ gw,
                            const float* __restrict__ gb,
                            int* __restrict__ cnt, int* __restrict__ tok,
                            float* __restrict__ wgt) {
    int wave = threadIdx.x >> 6;
    int lane = threadIdx.x & 63;
    int token = blockIdx.x * 4 + wave;
    const float* xr = x + (size_t)token * DDIM;
    float xv[16];
#pragma unroll
    for (int j = 0; j < 16; ++j) xv[j] = xr[lane + 64 * j];
    float lg[NEXP];
#pragma unroll
    for (int e = 0; e < NEXP; ++e) {
        const float* g = gw + e * DDIM;
        float s = 0.f;
#pragma unroll
        for (int j = 0; j < 16; ++j) s += xv[j] * g[lane + 64 * j];
#pragma unroll
        for (int o = 32; o > 0; o >>= 1) s += __shfl_xor(s, o, 64);
        lg[e] = s + gb[e];
    }
    if (lane == 0) {
        int i0 = 0; float v0 = lg[0];
        for (int e = 1; e < NEXP; ++e) if (lg[e] > v0) { v0 = lg[e]; i0 = e; }
        int i1 = -1; float v1 = -3.0e38f;
        for (int e = 0; e < NEXP; ++e) { if (e == i0) continue; if (lg[e] > v1) { v1 = lg[e]; i1 = e; } }
        float e1 = expf(v1 - v0);
        float den = 1.f + e1;
        float w0 = 1.f / den;
        float w1 = e1 / den;
        int p0 = atomicAdd(&cnt[i0], 1);
        tok[i0 * NTOK + p0] = token; wgt[i0 * NTOK + p0] = w0;
        int p1 = atomicAdd(&cnt[i1], 1);
        tok[i1 * NTOK + p1] = token; wgt[i1 * NTOK + p1] = w1;
    }
}

// ------ prefix scan of 128-padded expert counts + build tile work queues ----
// q1: GEMM1 entries (e, mt, nt<16)           entry: e | mt<<4 | nt<<12 | kc<<20
// q2: GEMM2 entries (e, mt, nt<4, kc<4)
__global__ void scan_kernel(const int* __restrict__ cnt, int* __restrict__ off,
                            int* __restrict__ q1, int* __restrict__ q2) {
    if (threadIdx.x == 0) {
        int acc = 0;
        for (int e = 0; e < NEXP; ++e) { off[e] = acc; acc += ((cnt[e] + 127) >> 7) << 7; }
        off[NEXP] = acc;
        int n1 = 0, n2 = 0;
        for (int e = 0; e < NEXP; ++e) {
            int mtiles = (cnt[e] + 255) >> 8;
            for (int mt = 0; mt < mtiles; ++mt) {
                for (int nt = 0; nt < IDIM / 256; ++nt)
                    q1[n1++] = e | (mt << 4) | (nt << 12);
                for (int kc = 0; kc < 4; ++kc)
                    for (int nt = 0; nt < DDIM / 256; ++nt)
                        q2[n2++] = e | (mt << 4) | (nt << 12) | (kc << 20);
            }
        }
        off[10] = n1; off[11] = n2;
    }
}

// ---------------- gather tokens into compacted fp16 activation rows ---------
__global__ void gather_kernel(const float* __restrict__ x, const int* __restrict__ cnt,
                              const int* __restrict__ off, const int* __restrict__ tok,
                              _Float16* __restrict__ xg) {
    int row = blockIdx.x;
    if (row >= off[NEXP]) return;
    int e = 0;
    while (e < NEXP - 1 && row >= off[e + 1]) ++e;
    int r = row - off[e];
    int t = threadIdx.x;
    _Float16* dst = xg + (size_t)row * DDIM;
    if (r < cnt[e]) {
        int token = tok[e * NTOK + r];
        float4 v = ((const float4*)(x + (size_t)token * DDIM))[t];
        f16x4 o = { (_Float16)v.x, (_Float16)v.y, (_Float16)v.z, (_Float16)v.w };
        ((f16x4*)dst)[t] = o;
    } else {
        f16x4 z = {};
        ((f16x4*)dst)[t] = z;   // zero padding rows so edge tiles are benign
    }
}

// ============================================================================
// Persistent 256x256 grouped GEMM, BK=32, 16 waves (4M x 4N, 64x64/wave),
// QUAD-buffered LDS (4 x 32 KiB = 128 KiB), prefetch 3 K-tiles ahead.
// Round-4 diagnosis: 21K cycles/iteration = latency-bound; 64 KB outstanding
// per CU with 1-iteration prefetch can't cover HBM latency. This version:
// 96 KB outstanding (16 waves x 6 glds), 3-iteration prefetch distance,
// steady-state s_waitcnt vmcnt(6) (never 0 mid-loop) [T3+T4].
// Per K-tile per wave: 1 A-glds + 1 B-glds (1 KiB each), 8 ds_read_b128,
// 16 MFMA (setprio-wrapped [T5]). Two barriers/iter: arrival + WAR.
// LDS swizzle (32-elem rows): phys slot = fq ^ ((row>>1)&3), staged via
// pre-swizzled global source (both-sides rule); 2-way banks = free.
// EPI==1: h = gelu(A@W1^T + b1) -> fp16.  EPI==2: out += w*(A@W2^T + b2).
// ============================================================================
#define SBAR() do { __builtin_amdgcn_s_barrier(); asm volatile("" ::: "memory"); } while (0)
#define STAGE(b, ko) do { \
    glds16(ap + (ko), &As[b][wv * 512]); \
    glds16(bp + (ko), &Bs[b][wv * 512]); \
} while (0)
#define ARD(buf, r) (*(const f16x8*)&As[buf][(r) * 32 + ((fq ^ (((r) >> 1) & 3)) << 3)])
#define BRD(buf, r) (*(const f16x8*)&Bs[buf][(r) * 32 + ((fq ^ (((r) >> 1) & 3)) << 3)])

template <int KDIM, int NDIM, int EPI, int SPLIT>
__global__ __launch_bounds__(1024, 4) void gemm256_kernel(
    const _Float16* __restrict__ A,     // [MAXPAD][KDIM] compacted rows
    const _Float16* __restrict__ Bw,    // [E][NDIM][KDIM] (K-major / B^T form)
    const float* __restrict__ bias,     // [E][NDIM]
    const int* __restrict__ cnt, const int* __restrict__ off,
    const int* __restrict__ tok, const float* __restrict__ wgt,
    _Float16* __restrict__ Hout, float* __restrict__ Out,
    const int* __restrict__ qarr, const int* __restrict__ qn) {
    constexpr int KB = KDIM / SPLIT;    // K elements per split group
    constexpr int NK = KB / 32;         // K-tiles of 32

    __shared__ __align__(16) _Float16 As[4][256 * 32];   // 4 x 16 KiB
    __shared__ __align__(16) _Float16 Bs[4][256 * 32];   // 4 x 16 KiB

    const int tid = threadIdx.x;
    const int wv = tid >> 6, lane = tid & 63;
    const int wm = (wv >> 2) * 64;      // wave row offset (4 waves in M)
    const int wn = (wv & 3) * 64;       // wave col offset (4 waves in N)
    const int fr = lane & 15, fq = lane >> 4;
    // staging: wave wv covers tile rows [wv*16, wv*16+16) each for A and B.
    // lane L -> row wv*16 + (L>>2), phys 16B slot L&3; source k-octet is
    // pre-swizzled: scol = ((L&3) ^ ((L>>3)&3)) * 8 elements.
    const int srow = lane >> 2;
    const int scol = ((lane & 3) ^ ((lane >> 3) & 3)) << 3;
    const int nwork = *qn;

    for (int wi = blockIdx.x; wi < nwork; wi += gridDim.x) {
        __syncthreads();                 // prev entry's LDS reads fully retired
        const int w = qarr[wi];
        const int e  = w & 15;
        const int mt = (w >> 4) & 255;
        const int nt = (w >> 12) & 255;
        const int kc = (w >> 20) & 7;
        const int ce = cnt[e];
        const int rowbase = off[e] + mt * 256;
        const int colbase = nt * 256;

        int ra = rowbase + wv * 16 + srow;
        if (ra > MAXPAD - 1) ra = MAXPAD - 1;   // clamp: garbage discarded in epilogue
        const _Float16* ap = A + (size_t)ra * KDIM + kc * KB + scol;
        const _Float16* bp = Bw + ((size_t)e * NDIM + colbase + wv * 16 + srow) * KDIM + kc * KB + scol;

        f32x4 acc[4][4] = {};

        // prologue: stage K-tiles 0..2 into buffers 0..2 (2 glds each)
        STAGE(0, 0); STAGE(1, 32); STAGE(2, 64);

        for (int kt = 0; kt < NK; ++kt) {
            const int buf = kt & 3;
            // issue K-tile kt+3 into buffer (kt+3)&3 (overwrites kt-1's buffer,
            // whose reads retired at the previous iteration's final barrier)
            if (kt + 3 < NK) STAGE((kt + 3) & 3, (kt + 3) * 32);
            const int ahead = (NK - 1 - kt) < 3 ? (NK - 1 - kt) : 3;
            if (ahead == 3)      asm volatile("s_waitcnt vmcnt(6)" ::: "memory");
            else if (ahead == 2) asm volatile("s_waitcnt vmcnt(4)" ::: "memory");
            else if (ahead == 1) asm volatile("s_waitcnt vmcnt(2)" ::: "memory");
            else                 asm volatile("s_waitcnt vmcnt(0)" ::: "memory");
            SBAR();   // all waves' kt-tile loads arrived
            f16x8 a[4], b[4];
#pragma unroll
            for (int i = 0; i < 4; ++i) a[i] = ARD(buf, wm + i * 16 + fr);
#pragma unroll
            for (int j = 0; j < 4; ++j) b[j] = BRD(buf, wn + j * 16 + fr);
            __builtin_amdgcn_s_setprio(1);
#pragma unroll
            for (int i = 0; i < 4; ++i)
#pragma unroll
                for (int j = 0; j < 4; ++j)
                    acc[i][j] = __builtin_amdgcn_mfma_f32_16x16x32_f16(a[i], b[j], acc[i][j], 0, 0, 0);
            __builtin_amdgcn_s_setprio(0);
            // all LDS reads of `buf` must retire before it is restaged
            asm volatile("s_waitcnt lgkmcnt(0)" ::: "memory");
            SBAR();
        }

        // -------- epilogue: acc[i][j] -> row wm+i*16+fq*4+r, col wn+j*16+fr --
        const int rq = fq << 2;
        if constexpr (EPI == 1) {
            const int elim = off[e + 1];   // stay inside this expert's padded region
#pragma unroll
            for (int i = 0; i < 4; ++i) {
#pragma unroll
                for (int r = 0; r < 4; ++r) {
                    const int grow = rowbase + wm + i * 16 + rq + r;
                    if (grow < elim) {
#pragma unroll
                        for (int j = 0; j < 4; ++j) {
                            const int col = colbase + wn + j * 16 + fr;
                            float v = fast_gelu(acc[i][j][r] + bias[e * NDIM + col]);
                            Hout[(size_t)grow * NDIM + col] = (_Float16)v;
                        }
                    }
                }
            }
        } else {
#pragma unroll
            for (int i = 0; i < 4; ++i) {
#pragma unroll
                for (int r = 0; r < 4; ++r) {
                    const int slot = mt * 256 + wm + i * 16 + rq + r;
                    if (slot < ce) {
                        const int token = tok[e * NTOK + slot];
                        const float ww = wgt[e * NTOK + slot];
#pragma unroll
                        for (int j = 0; j < 4; ++j) {
                            const int col = colbase + wn + j * 16 + fr;
                            float v = acc[i][j][r];
                            if (kc == 0) v += bias[e * NDIM + col];  // bias once per split group
                            unsafeAtomicAdd(&Out[(size_t)token * NDIM + col], ww * v);
                        }
                    }
                }
            }
        }
    }
}

extern "C" void kernel_launch(void* const* d_in, const int* in_sizes, int n_in,
                              void* d_out, int out_size, void* d_ws, size_t ws_size,
                              hipStream_t stream) {
    const float* x      = (const float*)d_in[0];
    const float* gate_w = (const float*)d_in[1];
    const float* gate_b = (const float*)d_in[2];
    const float* w1     = (const float*)d_in[3];
    const float* b1     = (const float*)d_in[4];
    const float* w2     = (const float*)d_in[5];
    const float* b2     = (const float*)d_in[6];
    float* out = (float*)d_out;

    // workspace layout (~218.5 MB)
    char* p = (char*)d_ws;
    _Float16* w1h  = (_Float16*)p; p += (size_t)NEXP * IDIM * DDIM * 2;  // 64 MB
    _Float16* w2h  = (_Float16*)p; p += (size_t)NEXP * DDIM * IDIM * 2;  // 64 MB
    _Float16* xg   = (_Float16*)p; p += (size_t)MAXPAD * DDIM * 2;       // 18 MB
    _Float16* hbuf = (_Float16*)p; p += (size_t)MAXPAD * IDIM * 2;       // 72 MB
    int*      tok  = (int*)p;      p += (size_t)NEXP * NTOK * 4;
    float*    wgt  = (float*)p;    p += (size_t)NEXP * NTOK * 4;
    int*      cnt  = (int*)p;      p += 128;   // [0..7] expert counts
    int*      off  = (int*)p;      p += 128;   // [0..8] offsets, [10] n1, [11] n2
    int*      q1   = (int*)p;      p += 4096;  // GEMM1 tile queue (1024 ints)
    int*      q2   = (int*)p;      p += 4096;  // GEMM2 tile queue (1024 ints)

    hipMemsetAsync(cnt, 0, 128, stream);
    hipMemsetAsync(out, 0, (size_t)NTOK * DDIM * 4, stream);

    // w2 FIRST so w1h is the L3-resident one when GEMM1 runs (round-4 lesson:
    // GEMM1 was ~460us because cvt(w2)'s 192 MB stream evicted w1h from L3).
    cvt_kernel<<<32768, 256, 0, stream>>>(w2, w2h, NEXP * DDIM * IDIM / 4);
    cvt_kernel<<<32768, 256, 0, stream>>>(w1, w1h, NEXP * IDIM * DDIM / 4);
    gate_kernel<<<NTOK / 4, 256, 0, stream>>>(x, gate_w, gate_b, cnt, tok, wgt);
    scan_kernel<<<1, 64, 0, stream>>>(cnt, off, q1, q2);
    gather_kernel<<<MAXPAD, 256, 0, stream>>>(x, cnt, off, tok, xg);

    // GEMM1: [rows x 1024] @ w1[e]^T -> gelu -> h [rows x 4096]
    // ~512 entries (8e x ~4mt x 16nt), grid 256 -> ~2 entries/block, NK=32
    gemm256_kernel<DDIM, IDIM, 1, 1><<<dim3(256), 1024, 0, stream>>>(
        xg, w1h, b1, cnt, off, tok, wgt, hbuf, (float*)nullptr, q1, off + 10);
    // GEMM2: [rows x 4096] @ w2[e]^T -> scaled scatter-add, split-K x4
    // ~512 entries (8e x ~4mt x 4nt x 4kc), grid 256 -> ~2/block, NK=32
    gemm256_kernel<IDIM, DDIM, 2, 4><<<dim3(256), 1024, 0, stream>>>(
        hbuf, w2h, b2, cnt, off, tok, wgt, (_Float16*)nullptr, out, q2, off + 11);
}

// Round 6
// 723.812 us; speedup vs baseline: 1.1636x; 1.0791x over previous
//
#include <hip/hip_runtime.h>
#include <math.h>

#define NTOK 4096
#define DDIM 1024
#define IDIM 4096
#define NEXP 8
#define MAXPAD 9216   // 8192 assignments + 8*128 worst-case 128-padded layout

typedef _Float16 f16x8 __attribute__((ext_vector_type(8)));
typedef _Float16 f16x4 __attribute__((ext_vector_type(4)));
typedef float    f32x4 __attribute__((ext_vector_type(4)));

// ---------------- async global->LDS, 16B per lane, lane-ordered LDS dest ----
__device__ __forceinline__ void glds16(const _Float16* g, _Float16* l) {
    __builtin_amdgcn_global_load_lds(
        (const __attribute__((address_space(1))) _Float16*)g,
        (__attribute__((address_space(3))) _Float16*)l, 16, 0, 0);
}

// tanh-approx GELU: |err| vs exact erf-GELU <= ~3e-3, far under our margin.
__device__ __forceinline__ float fast_gelu(float v) {
    float u = v * (0.7978845608f + 0.0356774081f * v * v);
    float ex = __builtin_amdgcn_exp2f(u * 2.8853900817779268f);  // exp(2u)
    float th = 1.0f - 2.0f * __builtin_amdgcn_rcpf(ex + 1.0f);   // tanh(u)
    return 0.5f * v * (1.0f + th);
}

// ---------------- fp32 -> fp16 weight conversion ----------------------------
__global__ void cvt_kernel(const float* __restrict__ src, _Float16* __restrict__ dst, int n4) {
    int i = blockIdx.x * blockDim.x + threadIdx.x;
    if (i >= n4) return;
    float4 v = ((const float4*)src)[i];
    f16x4 o = { (_Float16)v.x, (_Float16)v.y, (_Float16)v.z, (_Float16)v.w };
    ((f16x4*)dst)[i] = o;
}

// ---------------- gating: logits, top-2, softmax, atomic append -------------
__global__ void gate_kernel(const float* __restrict__ x, const float* __restrict__ gw,
                            const float* __restrict__ gb,
                            int* __restrict__ cnt, int* __restrict__ tok,
                            float* __restrict__ wgt) {
    int wave = threadIdx.x >> 6;
    int lane = threadIdx.x & 63;
    int token = blockIdx.x * 4 + wave;
    const float* xr = x + (size_t)token * DDIM;
    float xv[16];
#pragma unroll
    for (int j = 0; j < 16; ++j) xv[j] = xr[lane + 64 * j];
    float lg[NEXP];
#pragma unroll
    for (int e = 0; e < NEXP; ++e) {
        const float* g = gw + e * DDIM;
        float s = 0.f;
#pragma unroll
        for (int j = 0; j < 16; ++j) s += xv[j] * g[lane + 64 * j];
#pragma unroll
        for (int o = 32; o > 0; o >>= 1) s += __shfl_xor(s, o, 64);
        lg[e] = s + gb[e];
    }
    if (lane == 0) {
        int i0 = 0; float v0 = lg[0];
        for (int e = 1; e < NEXP; ++e) if (lg[e] > v0) { v0 = lg[e]; i0 = e; }
        int i1 = -1; float v1 = -3.0e38f;
        for (int e = 0; e < NEXP; ++e) { if (e == i0) continue; if (lg[e] > v1) { v1 = lg[e]; i1 = e; } }
        float e1 = expf(v1 - v0);
        float den = 1.f + e1;
        float w0 = 1.f / den;
        float w1 = e1 / den;
        int p0 = atomicAdd(&cnt[i0], 1);
        tok[i0 * NTOK + p0] = token; wgt[i0 * NTOK + p0] = w0;
        int p1 = atomicAdd(&cnt[i1], 1);
        tok[i1 * NTOK + p1] = token; wgt[i1 * NTOK + p1] = w1;
    }
}

// ------ prefix scan of 128-padded expert counts + build tile work queues ----
// M-tile = 128 rows (aligns exactly with the 128-padded layout -> no clamps).
// q1: GEMM1 (e, mt, nt<16)    q2: GEMM2 (e, mt, nt<4, kc<4)
// entry: e | mt<<4 | nt<<12 | kc<<20
__global__ void scan_kernel(const int* __restrict__ cnt, int* __restrict__ off,
                            int* __restrict__ q1, int* __restrict__ q2) {
    if (threadIdx.x == 0) {
        int acc = 0;
        for (int e = 0; e < NEXP; ++e) { off[e] = acc; acc += ((cnt[e] + 127) >> 7) << 7; }
        off[NEXP] = acc;
        int n1 = 0, n2 = 0;
        for (int e = 0; e < NEXP; ++e) {
            int mtiles = (cnt[e] + 127) >> 7;
            for (int mt = 0; mt < mtiles; ++mt) {
                for (int nt = 0; nt < IDIM / 256; ++nt)
                    q1[n1++] = e | (mt << 4) | (nt << 12);
                for (int kc = 0; kc < 4; ++kc)
                    for (int nt = 0; nt < DDIM / 256; ++nt)
                        q2[n2++] = e | (mt << 4) | (nt << 12) | (kc << 20);
            }
        }
        off[10] = n1; off[11] = n2;
    }
}

// ---------------- gather tokens into compacted fp16 activation rows ---------
__global__ void gather_kernel(const float* __restrict__ x, const int* __restrict__ cnt,
                              const int* __restrict__ off, const int* __restrict__ tok,
                              _Float16* __restrict__ xg) {
    int row = blockIdx.x;
    if (row >= off[NEXP]) return;
    int e = 0;
    while (e < NEXP - 1 && row >= off[e + 1]) ++e;
    int r = row - off[e];
    int t = threadIdx.x;
    _Float16* dst = xg + (size_t)row * DDIM;
    if (r < cnt[e]) {
        int token = tok[e * NTOK + r];
        float4 v = ((const float4*)(x + (size_t)token * DDIM))[t];
        f16x4 o = { (_Float16)v.x, (_Float16)v.y, (_Float16)v.z, (_Float16)v.w };
        ((f16x4*)dst)[t] = o;
    } else {
        f16x4 z = {};
        ((f16x4*)dst)[t] = z;   // zero padding rows so edge tiles are benign
    }
}

// ============================================================================
// Persistent 128x256 grouped GEMM, BK=32, 8 waves (2M x 4N, 64x64/wave),
// double-buffered 48 KiB LDS -> TWO blocks/CU (launch_bounds(512,4); per-wave
// regs ~124 incl. 64 AGPR acc, proven by R5's 60-VGPR compile).
// KEY FIX vs rounds 1-5: NO "memory" clobbers on waitcnt asm / barriers.
// Clobbered asm forces hipcc to insert s_waitcnt vmcnt(0) lgkmcnt(0) before
// each sync point -> every prior "counted vmcnt" schedule was secretly
// synchronous (staging pinned at 3.6 B/cyc/CU across R2/R4/R5 regardless of
// prefetch depth). This follows the verified m201 pattern: bare s_barrier
// builtin + bare `asm volatile("s_waitcnt ...")` + sched_barrier(0) fences.
// Per K-tile per wave: 3 glds (24 rows of 32 halfs), vmcnt(3) steady (next
// tile's 3 stay in flight), 8 ds_read_b128, 16 MFMA (setprio-wrapped).
// XOR swizzle identical to R5 (measured SQ_LDS_BANK_CONFLICT = 0).
// EPI==1: h = gelu(A@W1^T + b1) -> fp16.  EPI==2: out += w*(A@W2^T + b2).
// ============================================================================
#define STAGE(b, ko) do { \
    glds16(gp0 + (ko), &Sh[b][lo0]); \
    glds16(gp1 + (ko), &Sh[b][lo1]); \
    glds16(gp2 + (ko), &Sh[b][lo2]); \
} while (0)
#define ARD(buf, r) (*(const f16x8*)&Sh[buf][(r) * 32 + ((fq ^ (((r) >> 1) & 3)) << 3)])
#define BRD(buf, r) (*(const f16x8*)&Sh[buf][4096 + (r) * 32 + ((fq ^ (((r) >> 1) & 3)) << 3)])

template <int KDIM, int NDIM, int EPI, int SPLIT>
__global__ __launch_bounds__(512, 4) void gemm256_kernel(
    const _Float16* __restrict__ A,     // [MAXPAD][KDIM] compacted rows
    const _Float16* __restrict__ Bw,    // [E][NDIM][KDIM] (K-major / B^T form)
    const float* __restrict__ bias,     // [E][NDIM]
    const int* __restrict__ cnt, const int* __restrict__ off,
    const int* __restrict__ tok, const float* __restrict__ wgt,
    _Float16* __restrict__ Hout, float* __restrict__ Out,
    const int* __restrict__ qarr, const int* __restrict__ qn) {
    constexpr int KB = KDIM / SPLIT;    // K elements per split group
    constexpr int NK = KB / 32;         // K-tiles of 32

    // [0..4095] = A (128 rows x 32), [4096..12287] = B (256 rows x 32)
    __shared__ __align__(16) _Float16 Sh[2][384 * 32];   // 2 x 24 KiB

    const int tid = threadIdx.x;
    const int wv = tid >> 6, lane = tid & 63;
    const int wm = (wv >> 2) * 64;      // wave row offset (2 waves in M)
    const int wn = (wv & 3) * 64;       // wave col offset (4 waves in N)
    const int fr = lane & 15, fq = lane >> 4;
    // staging: glds id g covers 16 rows x 32 halfs (1 KiB). ids 0..7 = A,
    // ids 8..23 = B. Wave wv owns ids 3wv..3wv+2. lane L -> row base + (L>>2),
    // 16B slot L&3; source k-octet pre-swizzled (R5-verified pair):
    const int srow = lane >> 2;
    const int scol = ((lane & 3) ^ ((lane >> 3) & 3)) << 3;
    const int nwork = *qn;

    for (int wi = blockIdx.x; wi < nwork; wi += gridDim.x) {
        __syncthreads();                 // prev entry fully done (full drain, 1/entry)
        const int w = qarr[wi];
        const int e  = w & 15;
        const int mt = (w >> 4) & 63;
        const int nt = (w >> 12) & 31;
        const int kc = (w >> 20) & 7;
        const int ce = cnt[e];
        const int rowbase = off[e] + mt * 128;
        const int colbase = nt * 256;

        const int id0 = wv * 3, id1 = wv * 3 + 1, id2 = wv * 3 + 2;
        const _Float16* gp0; const _Float16* gp1; const _Float16* gp2;
        int lo0, lo1, lo2;
        {
            const _Float16* Ab = A + (size_t)rowbase * KDIM + kc * KB + scol;
            const _Float16* Bb = Bw + ((size_t)e * NDIM + colbase) * KDIM + kc * KB + scol;
            gp0 = (id0 < 8) ? Ab + (size_t)(id0 * 16 + srow) * KDIM
                            : Bb + (size_t)((id0 - 8) * 16 + srow) * KDIM;
            gp1 = (id1 < 8) ? Ab + (size_t)(id1 * 16 + srow) * KDIM
                            : Bb + (size_t)((id1 - 8) * 16 + srow) * KDIM;
            gp2 = Bb + (size_t)((id2 - 8) * 16 + srow) * KDIM;   // id2 >= 8 always? no: wv=0..1 -> id2=2,5 <8
            if (id2 < 8) gp2 = Ab + (size_t)(id2 * 16 + srow) * KDIM;
            lo0 = (id0 < 8) ? id0 * 512 : 4096 + (id0 - 8) * 512;
            lo1 = (id1 < 8) ? id1 * 512 : 4096 + (id1 - 8) * 512;
            lo2 = (id2 < 8) ? id2 * 512 : 4096 + (id2 - 8) * 512;
        }

        f32x4 acc[4][4] = {};

        // prologue: stage K-tile 0 into buffer 0 (3 glds per wave)
        STAGE(0, 0);

        for (int kt = 0; kt < NK; ++kt) {
            const int cur = kt & 1, nxt = cur ^ 1;
            if (kt + 1 < NK) {
                STAGE(nxt, (kt + 1) * 32);              // next tile: 3 glds in flight
                asm volatile("s_waitcnt vmcnt(3)");     // cur's 3 arrived (NO clobber!)
            } else {
                asm volatile("s_waitcnt vmcnt(0)");
            }
            __builtin_amdgcn_s_barrier();               // all waves' cur tile ready
            __builtin_amdgcn_sched_barrier(0);          // pin: nothing crosses up
            f16x8 a[4], b[4];
#pragma unroll
            for (int i = 0; i < 4; ++i) a[i] = ARD(cur, wm + i * 16 + fr);
#pragma unroll
            for (int j = 0; j < 4; ++j) b[j] = BRD(cur, wn + j * 16 + fr);
            __builtin_amdgcn_s_setprio(1);
#pragma unroll
            for (int i = 0; i < 4; ++i)
#pragma unroll
                for (int j = 0; j < 4; ++j)
                    acc[i][j] = __builtin_amdgcn_mfma_f32_16x16x32_f16(a[i], b[j], acc[i][j], 0, 0, 0);
            __builtin_amdgcn_s_setprio(0);
            __builtin_amdgcn_sched_barrier(0);          // pin: ds_reads can't sink
            asm volatile("s_waitcnt lgkmcnt(0)");       // LDS reads retired (WAR safe)
            __builtin_amdgcn_s_barrier();
        }

        // ------- epilogue: acc[i][j] -> row wm+i*16+fq*4+r, col wn+j*16+fr ---
        const int rq = fq << 2;
        if constexpr (EPI == 1) {
#pragma unroll
            for (int i = 0; i < 4; ++i) {
#pragma unroll
                for (int r = 0; r < 4; ++r) {
                    const int grow = rowbase + wm + i * 16 + rq + r;   // always in-region
#pragma unroll
                    for (int j = 0; j < 4; ++j) {
                        const int col = colbase + wn + j * 16 + fr;
                        float v = fast_gelu(acc[i][j][r] + bias[e * NDIM + col]);
                        Hout[(size_t)grow * NDIM + col] = (_Float16)v;
                    }
                }
            }
        } else {
#pragma unroll
            for (int i = 0; i < 4; ++i) {
#pragma unroll
                for (int r = 0; r < 4; ++r) {
                    const int slot = mt * 128 + wm + i * 16 + rq + r;
                    if (slot < ce) {
                        const int token = tok[e * NTOK + slot];
                        const float ww = wgt[e * NTOK + slot];
#pragma unroll
                        for (int j = 0; j < 4; ++j) {
                            const int col = colbase + wn + j * 16 + fr;
                            float v = acc[i][j][r];
                            if (kc == 0) v += bias[e * NDIM + col];  // bias once per split group
                            unsafeAtomicAdd(&Out[(size_t)token * NDIM + col], ww * v);
                        }
                    }
                }
            }
        }
    }
}

extern "C" void kernel_launch(void* const* d_in, const int* in_sizes, int n_in,
                              void* d_out, int out_size, void* d_ws, size_t ws_size,
                              hipStream_t stream) {
    const float* x      = (const float*)d_in[0];
    const float* gate_w = (const float*)d_in[1];
    const float* gate_b = (const float*)d_in[2];
    const float* w1     = (const float*)d_in[3];
    const float* b1     = (const float*)d_in[4];
    const float* w2     = (const float*)d_in[5];
    const float* b2     = (const float*)d_in[6];
    float* out = (float*)d_out;

    // workspace layout (~218.5 MB)
    char* p = (char*)d_ws;
    _Float16* w1h  = (_Float16*)p; p += (size_t)NEXP * IDIM * DDIM * 2;  // 64 MB
    _Float16* w2h  = (_Float16*)p; p += (size_t)NEXP * DDIM * IDIM * 2;  // 64 MB
    _Float16* xg   = (_Float16*)p; p += (size_t)MAXPAD * DDIM * 2;       // 18 MB
    _Float16* hbuf = (_Float16*)p; p += (size_t)MAXPAD * IDIM * 2;       // 72 MB
    int*      tok  = (int*)p;      p += (size_t)NEXP * NTOK * 4;
    float*    wgt  = (float*)p;    p += (size_t)NEXP * NTOK * 4;
    int*      cnt  = (int*)p;      p += 128;   // [0..7] expert counts
    int*      off  = (int*)p;      p += 128;   // [0..8] offsets, [10] n1, [11] n2
    int*      q1   = (int*)p;      p += 8192;  // GEMM1 tile queue (2048 ints)
    int*      q2   = (int*)p;      p += 8192;  // GEMM2 tile queue (2048 ints)

    hipMemsetAsync(cnt, 0, 128, stream);
    hipMemsetAsync(out, 0, (size_t)NTOK * DDIM * 4, stream);

    // w2 first so w1h stays L3-resident when GEMM1 runs.
    cvt_kernel<<<32768, 256, 0, stream>>>(w2, w2h, NEXP * DDIM * IDIM / 4);
    cvt_kernel<<<32768, 256, 0, stream>>>(w1, w1h, NEXP * IDIM * DDIM / 4);
    gate_kernel<<<NTOK / 4, 256, 0, stream>>>(x, gate_w, gate_b, cnt, tok, wgt);
    scan_kernel<<<1, 64, 0, stream>>>(cnt, off, q1, q2);
    gather_kernel<<<MAXPAD, 256, 0, stream>>>(x, cnt, off, tok, xg);

    // GEMM1: [rows x 1024] @ w1[e]^T -> gelu -> h [rows x 4096]
    // ~1056 entries (8e x ~8mt x 16nt), grid 512 (2 blocks/CU) -> ~2/block
    gemm256_kernel<DDIM, IDIM, 1, 1><<<dim3(512), 512, 0, stream>>>(
        xg, w1h, b1, cnt, off, tok, wgt, hbuf, (float*)nullptr, q1, off + 10);
    // GEMM2: [rows x 4096] @ w2[e]^T -> scaled scatter-add, split-K x4
    // ~1056 entries (8e x ~8mt x 4nt x 4kc) -> ~2/block, NK=32
    gemm256_kernel<IDIM, DDIM, 2, 4><<<dim3(512), 512, 0, stream>>>(
        hbuf, w2h, b2, cnt, off, tok, wgt, (_Float16*)nullptr, out, q2, off + 11);
}